// Round 8
// baseline (401.063 us; speedup 1.0000x reference)
//
#include <hip/hip_runtime.h>
#include <math.h>

#define TLEN 2048

typedef __attribute__((ext_vector_type(8))) short bf16x8;
typedef __attribute__((ext_vector_type(4))) float f32x4;

__device__ __forceinline__ unsigned fbits(float x){ union{float f; unsigned u;} a; a.f=x; return a.u; }
__device__ __forceinline__ float bitsf(unsigned u){ union{unsigned u; float f;} a; a.u=u; return a.f; }
// fp32 -> bf16 round-to-nearest-even
__device__ __forceinline__ unsigned short f2b(float x){
  unsigned u = fbits(x);
  return (unsigned short)((u + 0x7fffu + ((u>>16)&1u)) >> 16);
}

// Swapped-layout MFMA flash attention, one (bh, 64-t-tile) per block, 4 waves.
// R7 measured ~150us: LDS-issue bound (~520 DS cyc/wave/tile vs ~190 MFMA) with
// global K/V load latency exposed inside the barrier-lockstep staging phase.
// R8: T14 register double-buffer — prefetch tile st+1 (K,V,W) into regs during
// tile st's compute; staging phase becomes convert+ds_write only. Manual 2x
// unroll (ping-pong A/B buffers) avoids per-tile register copies. T5 setprio
// around MFMA clusters. Math bit-identical to R7 (absmax must stay 9.77e-4).
__global__ __launch_bounds__(256, 2)
void wqkv_attn_mfma(const float* __restrict__ qkv,
                    const float* __restrict__ wm,
                    float* __restrict__ out) {
  const int bh = blockIdx.x & 15;          // head fastest: 2 heads/XCD resident in L2
  const int t0 = (blockIdx.x >> 4) << 6;
  const int b  = bh >> 3;
  const int h  = bh & 7;
  const int tid  = threadIdx.x;
  const int w    = tid >> 6;               // wave 0..3, owns t-strip [16w,16w+16)
  const int lane = tid & 63;
  const int lt   = lane & 15;
  const int q4   = lane >> 4;

  __shared__ __align__(16) unsigned short Qhi[64][64], Qlo[64][64]; // [t][c]
  __shared__ __align__(16) unsigned short Khi[64][72], Klo[64][72]; // [s][c] swizzled
  __shared__ __align__(16) unsigned short Vhi[64][72], Vlo[64][72]; // [c][s]
  __shared__ __align__(16) unsigned short Pl [64][72];              // [t][s]

  const float* qb   = qkv + ((size_t)b*1536 + (size_t)h*64) * TLEN;
  const float* kb   = qb + (size_t)512  * TLEN;
  const float* vb   = qb + (size_t)1024 * TLEN;
  const float* wmat = wm + (size_t)bh * TLEN * TLEN;

  // ---- Q prologue: global [c][t] fp32 -> LDS [t][c] hi/lo bf16 ----
  #pragma unroll
  for (int j = 0; j < 4; ++j) {
    int flat = tid + j*256;
    int c = flat >> 4, u = flat & 15;
    float4 v = *(const float4*)(qb + (size_t)c*TLEN + t0 + 4*u);
    float xs[4] = {v.x, v.y, v.z, v.w};
    #pragma unroll
    for (int i = 0; i < 4; ++i) {
      unsigned hb = fbits(xs[i]) & 0xffff0000u;
      Qhi[4*u+i][c] = (unsigned short)(hb >> 16);
      Qlo[4*u+i][c] = f2b(xs[i] - bitsf(hb));
    }
  }
  __syncthreads();

  // Hoist Q B-frags: lane: t=16w+lt, c=32kc+8q4+j
  bf16x8 qfh[2], qfl[2];
  #pragma unroll
  for (int kc = 0; kc < 2; ++kc) {
    qfh[kc] = *(const bf16x8*)&Qhi[16*w + lt][32*kc + 8*q4];
    qfl[kc] = *(const bf16x8*)&Qlo[16*w + lt][32*kc + 8*q4];
  }

  f32x4 accO[4];
  #pragma unroll
  for (int i = 0; i < 4; ++i) accO[i] = (f32x4){0.f,0.f,0.f,0.f};
  float m_run = -1e30f, l_run = 0.0f;

  // per-thread staging coords (constant across tiles)
  const int stg_c = tid >> 4;              // wait, flat=tid+j*256 -> c varies with j; keep in-loop
  (void)stg_c;

  // ---- prefetch helpers ----
  auto load_kv = [&](int s0n, float4 (&kN)[4], float4 (&vN)[4]) {
    #pragma unroll
    for (int j = 0; j < 4; ++j) {
      int flat = tid + j*256;
      int c = flat >> 4, u = flat & 15;
      kN[j] = *(const float4*)(kb + (size_t)c*TLEN + s0n + 4*u);
      vN[j] = *(const float4*)(vb + (size_t)c*TLEN + s0n + 4*u);
    }
  };
  auto load_w = [&](int s0n, float4 (&wN)[4]) {
    #pragma unroll
    for (int fm = 0; fm < 4; ++fm)
      wN[fm] = *(const float4*)(wmat + (size_t)(t0 + 16*w + lt)*TLEN + s0n + 16*fm + 4*q4);
  };

  // ---- tile body: stage cur regs -> LDS, prefetch next into nxt regs, compute ----
  auto tile_body = [&](int st, float4 (&kC)[4], float4 (&vC)[4], float4 (&wC)[4],
                               float4 (&kN)[4], float4 (&vN)[4], float4 (&wN)[4]) {
    // stage K (transposed [s][c], swizzled) and V ([c][s]) hi/lo from regs
    #pragma unroll
    for (int j = 0; j < 4; ++j) {
      int flat = tid + j*256;
      int c = flat >> 4, u = flat & 15;
      int pc = c ^ (8*(u & 7));
      float ks[4] = {kC[j].x, kC[j].y, kC[j].z, kC[j].w};
      #pragma unroll
      for (int i = 0; i < 4; ++i) {
        unsigned hb = fbits(ks[i]) & 0xffff0000u;
        Khi[4*u+i][pc] = (unsigned short)(hb >> 16);
        Klo[4*u+i][pc] = f2b(ks[i] - bitsf(hb));
      }
      float4 vv = vC[j];
      unsigned xh = (fbits(vv.x)>>16) | (fbits(vv.y) & 0xffff0000u);
      unsigned yh = (fbits(vv.z)>>16) | (fbits(vv.w) & 0xffff0000u);
      unsigned xl = (unsigned)f2b(vv.x - bitsf(fbits(vv.x)&0xffff0000u))
                  | ((unsigned)f2b(vv.y - bitsf(fbits(vv.y)&0xffff0000u)) << 16);
      unsigned yl = (unsigned)f2b(vv.z - bitsf(fbits(vv.z)&0xffff0000u))
                  | ((unsigned)f2b(vv.w - bitsf(fbits(vv.w)&0xffff0000u)) << 16);
      *(uint2*)&Vhi[c][4*u] = make_uint2(xh, yh);
      *(uint2*)&Vlo[c][4*u] = make_uint2(xl, yl);
    }
    __syncthreads();   // tile st staged; all waves may read

    // prefetch tile st+1 into regs (latency hides under QK+softmax+PV)
    if (st + 1 < 32) {
      load_kv((st+1)*64, kN, vN);
      load_w ((st+1)*64, wN);
    }

    // ---- QK^T: acc[fm] = S^T rows s=16fm+4q4+reg, col t=16w+lt ----
    f32x4 acc[4];
    __builtin_amdgcn_s_setprio(1);
    #pragma unroll
    for (int fm = 0; fm < 4; ++fm) {
      f32x4 a = (f32x4){0.f,0.f,0.f,0.f};
      const int srow = 16*fm + lt;
      const int f = (4*fm + (lt >> 2)) & 7;
      #pragma unroll
      for (int kc = 0; kc < 2; ++kc) {
        const int blk = (4*kc + q4) ^ f;
        bf16x8 kh = *(const bf16x8*)&Khi[srow][8*blk];
        bf16x8 kl = *(const bf16x8*)&Klo[srow][8*blk];
        a = __builtin_amdgcn_mfma_f32_16x16x32_bf16(kh, qfh[kc], a, 0,0,0);
        a = __builtin_amdgcn_mfma_f32_16x16x32_bf16(kh, qfl[kc], a, 0,0,0);
        a = __builtin_amdgcn_mfma_f32_16x16x32_bf16(kl, qfh[kc], a, 0,0,0);
      }
      acc[fm] = a;
    }
    __builtin_amdgcn_s_setprio(0);

    // ---- weight-mult + online softmax (lane-local column t) ----
    float sv[4][4];
    float mx = -1e30f;
    #pragma unroll
    for (int fm = 0; fm < 4; ++fm) {
      float wvf[4] = {wC[fm].x, wC[fm].y, wC[fm].z, wC[fm].w};
      #pragma unroll
      for (int r = 0; r < 4; ++r) {
        float x = acc[fm][r] * 0.125f * wvf[r];
        sv[fm][r] = x;
        mx = fmaxf(mx, x);
      }
    }
    mx = fmaxf(mx, __shfl_xor(mx, 16));
    mx = fmaxf(mx, __shfl_xor(mx, 32));
    const float mn   = fmaxf(m_run, mx);
    const float corr = __expf(m_run - mn);
    m_run = mn;
    float sum = 0.f;
    unsigned short pb[4][4];
    #pragma unroll
    for (int fm = 0; fm < 4; ++fm)
      #pragma unroll
      for (int r = 0; r < 4; ++r) {
        float p = __expf(sv[fm][r] - mn);
        sum += p;
        pb[fm][r] = f2b(p);
      }
    sum += __shfl_xor(sum, 16);
    sum += __shfl_xor(sum, 32);
    l_run = l_run * corr + sum;
    #pragma unroll
    for (int fm = 0; fm < 4; ++fm)
      #pragma unroll
      for (int r = 0; r < 4; ++r)
        accO[fm][r] *= corr;

    // ---- write P rows (wave-private: rows 16w+lt) ----
    #pragma unroll
    for (int fm = 0; fm < 4; ++fm) {
      unsigned p01 = (unsigned)pb[fm][0] | ((unsigned)pb[fm][1] << 16);
      unsigned p23 = (unsigned)pb[fm][2] | ((unsigned)pb[fm][3] << 16);
      *(uint2*)&Pl[16*w + lt][16*fm + 4*q4] = make_uint2(p01, p23);
    }

    // ---- PV: accO[fm] += mfma(A=V rows c=16fm+lt, B=P) ----
    __builtin_amdgcn_s_setprio(1);
    #pragma unroll
    for (int kc = 0; kc < 2; ++kc) {
      bf16x8 pf = *(const bf16x8*)&Pl[16*w + lt][32*kc + 8*q4];
      #pragma unroll
      for (int fm = 0; fm < 4; ++fm) {
        bf16x8 vh = *(const bf16x8*)&Vhi[16*fm + lt][32*kc + 8*q4];
        bf16x8 vl = *(const bf16x8*)&Vlo[16*fm + lt][32*kc + 8*q4];
        accO[fm] = __builtin_amdgcn_mfma_f32_16x16x32_bf16(vh, pf, accO[fm], 0,0,0);
        accO[fm] = __builtin_amdgcn_mfma_f32_16x16x32_bf16(vl, pf, accO[fm], 0,0,0);
      }
    }
    __builtin_amdgcn_s_setprio(0);

    __syncthreads();   // protect K/V/P LDS before next staging
  };

  // ---- prologue prefetch + 2x-unrolled main loop (ping-pong A/B) ----
  float4 kA[4], vA[4], wA[4], kB[4], vB[4], wB[4];
  load_kv(0, kA, vA);
  load_w (0, wA);
  for (int st = 0; st < 32; st += 2) {
    tile_body(st,     kA, vA, wA, kB, vB, wB);
    tile_body(st + 1, kB, vB, wB, kA, vA, wA);
  }

  // ---- epilogue: normalize, store out[b][h*64+c][t0+16w+lt] ----
  const float inv = 1.0f / l_run;
  #pragma unroll
  for (int fm = 0; fm < 4; ++fm)
    #pragma unroll
    for (int r = 0; r < 4; ++r) {
      int c = 16*fm + 4*q4 + r;
      out[((size_t)b*512 + (size_t)h*64 + c)*TLEN + t0 + 16*w + lt] = accO[fm][r] * inv;
    }
}

extern "C" void kernel_launch(void* const* d_in, const int* in_sizes, int n_in,
                              void* d_out, int out_size, void* d_ws, size_t ws_size,
                              hipStream_t stream) {
  const float* qkv = (const float*)d_in[0];     // (2, 1536, 2048) fp32
  const float* wm  = (const float*)d_in[1];     // (16, 2048, 2048) fp32
  float* out = (float*)d_out;                   // (2, 512, 2048) fp32
  dim3 grid(512);
  dim3 block(256);
  hipLaunchKernelGGL(wqkv_attn_mfma, grid, block, 0, stream, qkv, wm, out);
}